// Round 4
// baseline (198.416 us; speedup 1.0000x reference)
//
#include <hip/hip_runtime.h>
#include <cstdint>

#define DEVI __device__ __forceinline__

using fx4 = __attribute__((ext_vector_type(4))) float;
using bf8 = __attribute__((ext_vector_type(8))) __bf16;
using s8v = __attribute__((ext_vector_type(8))) short;
using s4v = __attribute__((ext_vector_type(4))) short;
typedef unsigned short u16;
typedef unsigned int u32;

DEVI float b2f(u16 u) { return __builtin_bit_cast(float, (u32)u << 16); }
DEVI u16 f2b(float f) {
  u32 u = __builtin_bit_cast(u32, f);
  return (u16)((u + 0x7fffu + ((u >> 16) & 1u)) >> 16);
}

// async global->LDS, 16B per lane, dest = wave-uniform base + lane*16
#define GLOAD(g, l)                                                          \
  __builtin_amdgcn_global_load_lds(                                          \
      (const __attribute__((address_space(1))) unsigned int*)(g),            \
      (__attribute__((address_space(3))) unsigned int*)(l), 16, 0, 0)

// ---- weight prep: W0->bf16, Wqk2=[Wq|Wq ; Wk|Wk] bf16, WvT bf16 ----
__global__ __launch_bounds__(256) void prep(const float* __restrict__ W0,
                                            const float* __restrict__ Wq,
                                            const float* __restrict__ Wk,
                                            const float* __restrict__ Wv,
                                            u16* __restrict__ w0b,
                                            u16* __restrict__ wqk2,
                                            u16* __restrict__ wvtb) {
  const int i = blockIdx.x * 256 + threadIdx.x;
  if (blockIdx.y == 0) {
    if (i < 131072) w0b[i] = f2b(W0[i]);
  } else if (blockIdx.y == 1) {
    if (i < 524288) {
      const int row = i >> 9, c = i & 511;
      const float* src = (row < 256) ? Wq : Wk;
      wqk2[i] = f2b(src[((row & 255) << 8) + (c & 255)]);
    }
  } else {
    if (i < 65536) {
      const int e = i >> 8, d = i & 255;
      wvtb[i] = f2b(Wv[d * 256 + e]);   // WvT[e,d] = Wv[d,e]
    }
  }
}

// ---- Wc = Wsp @ Wp (bf16), bc = Wsp @ bp (fp32) ----
__global__ __launch_bounds__(256) void wcmul(const float* __restrict__ Wsp,
                                             const float* __restrict__ Wp,
                                             const float* __restrict__ bp,
                                             u16* __restrict__ wcb, float* __restrict__ bc) {
  const int o = blockIdx.x, t = threadIdx.x;
  __shared__ float row[256];
  __shared__ float red[4];
  row[t] = Wsp[o * 256 + t];
  __syncthreads();
  float acc = 0.f;
  for (int c = 0; c < 256; ++c) acc += row[c] * Wp[c * 256 + t];
  wcb[o * 256 + t] = f2b(acc);
  float pb = row[t] * bp[t];
#pragma unroll
  for (int m = 32; m > 0; m >>= 1) pb += __shfl_xor(pb, m);
  if ((t & 63) == 0) red[t >> 6] = pb;
  __syncthreads();
  if (t == 0) bc[o] = red[0] + red[1] + red[2] + red[3];
}

// ---- concat + transpose: fd,fs [B,C,N] fp32 -> cat_t [B,N,2C] bf16 ----
__global__ void pack_cat(const float* __restrict__ fd, const float* __restrict__ fs,
                         u16* __restrict__ out) {
  __shared__ float t[32][33];
  const int b = blockIdx.z;
  const int n0 = blockIdx.x * 32;
  const int g = blockIdx.y;
  const float* src = (g < 8) ? fd : fs;
  const int c0 = (g & 7) * 32;
  const int ccol0 = g * 32;
  const int tx = threadIdx.x;
  const int ty = threadIdx.y;
  const float* sp = src + ((long)b * 256 + c0) * 4096 + n0;
#pragma unroll
  for (int i = 0; i < 4; ++i) {
    int c = ty + i * 8;
    t[c][tx] = sp[(long)c * 4096 + tx];
  }
  __syncthreads();
  u16* op = out + ((long)b * 4096 + n0) * 512 + ccol0;
#pragma unroll
  for (int i = 0; i < 4; ++i) {
    int r = ty + i * 8;
    op[(long)r * 512 + tx] = f2b(t[tx][r]);
  }
}

// ---- bf16 NT GEMM: C[m,n] = sum_k A[m,k]*B[n,k] ----
// 128x128 tile, BK=64, 4 waves; global_load_lds(16B) staging with
// pre-swizzled SOURCE address (LDS dest linear, XOR-swizzled read).
// BIAS: 0 none, 2 bias[m]. POOL: per-tile row sums.
// EPI: 0 normal C write; 1 = S2 hi/lo write (rows<256) + diag partials.
template <typename OT, int BIAS, bool POOL, int EPI>
__global__ __launch_bounds__(256) void gemm_nt(
    const u16* __restrict__ A, long sA, int lda,
    const u16* __restrict__ B, long sB, int ldb,
    OT* __restrict__ C, long sC, long sCs, int ldc,
    const float* __restrict__ bias, int Keff, int ksplit,
    float* __restrict__ poolpart,
    const float* __restrict__ wqf, const float* __restrict__ wkf,
    float* __restrict__ dpart) {
  __shared__ u16 ldsA[128 * 64];
  __shared__ u16 ldsB[128 * 64];
  const int z = blockIdx.z;
  const int bb = z / ksplit;
  const int ss = z - bb * ksplit;
  const int bm = blockIdx.x * 128;
  const int bn = blockIdx.y * 128;
  const u16* Ab = A + bb * sA + (long)ss * Keff + (long)bm * lda;
  const u16* Bb = B + bb * sB + (long)ss * Keff + (long)bn * ldb;
  const int tid = threadIdx.x;
  const int wid = tid >> 6;
  const int lane = tid & 63;
  const int wm = wid >> 1, wn = wid & 1;
  const int srow = tid >> 3;
  const int slot = tid & 7;

  fx4 acc[4][4] = {};
  for (int kt = 0; kt < Keff; kt += 64) {
#pragma unroll
    for (int i = 0; i < 4; ++i) {
      const int row = i * 32 + srow;
      const int kq = slot ^ (row & 7);
      GLOAD(Ab + (long)row * lda + kt + kq * 8, &ldsA[i * 2048 + wid * 512]);
      GLOAD(Bb + (long)row * ldb + kt + kq * 8, &ldsB[i * 2048 + wid * 512]);
    }
    __syncthreads();
#pragma unroll
    for (int ko = 0; ko < 2; ++ko) {
      bf8 af[4], bfr[4];
      const int kq = ko * 4 + (lane >> 4);
#pragma unroll
      for (int f = 0; f < 4; ++f) {
        const int ar = wm * 64 + f * 16 + (lane & 15);
        af[f] = *(const bf8*)&ldsA[ar * 64 + ((kq ^ (ar & 7)) * 8)];
        const int br = wn * 64 + f * 16 + (lane & 15);
        bfr[f] = *(const bf8*)&ldsB[br * 64 + ((kq ^ (br & 7)) * 8)];
      }
#pragma unroll
      for (int fm = 0; fm < 4; ++fm)
#pragma unroll
        for (int fn = 0; fn < 4; ++fn)
          acc[fm][fn] = __builtin_amdgcn_mfma_f32_16x16x32_bf16(af[fm], bfr[fn], acc[fm][fn], 0, 0, 0);
    }
    __syncthreads();
  }
  if constexpr (EPI == 1) {
    // S2 hi/lo write for rows<256 + diag partials for all rows
    u16* S2b = (u16*)C + bb * sC;
    float dp[4][4];
#pragma unroll
    for (int fm = 0; fm < 4; ++fm)
#pragma unroll
      for (int r = 0; r < 4; ++r) dp[fm][r] = 0.f;
#pragma unroll
    for (int fm = 0; fm < 4; ++fm) {
      const int m0 = bm + wm * 64 + fm * 16 + ((lane >> 4) << 2);
#pragma unroll
      for (int fn = 0; fn < 4; ++fn) {
        const int n0 = bn + wn * 64 + fn * 16 + (lane & 15);
#pragma unroll
        for (int r = 0; r < 4; ++r) {
          const float v = acc[fm][fn][r];
          const int m = m0 + r;
          if (m < 256) {
            const u16 hi = f2b(v);
            S2b[(long)m * 512 + n0] = hi;
            S2b[(long)m * 512 + 256 + n0] = f2b(v - b2f(hi));
          }
          const float* wr = (m < 256) ? (wqf + (long)m * 256) : (wkf + (long)(m - 256) * 256);
          dp[fm][r] += v * wr[n0];
        }
      }
    }
#pragma unroll
    for (int fm = 0; fm < 4; ++fm)
#pragma unroll
      for (int r = 0; r < 4; ++r) {
        float s = dp[fm][r];
        s += __shfl_xor(s, 1); s += __shfl_xor(s, 2);
        s += __shfl_xor(s, 4); s += __shfl_xor(s, 8);
        if ((lane & 15) == 0) {
          const int m = bm + wm * 64 + fm * 16 + ((lane >> 4) << 2) + r;
          dpart[(long)(blockIdx.y * 2 + wn) * 4096 + bb * 512 + m] = s;
        }
      }
    return;
  }
  OT* Cb = C + bb * sC + ss * sCs;
  float pr[4][4];
  if (POOL) {
#pragma unroll
    for (int fm = 0; fm < 4; ++fm)
#pragma unroll
      for (int r = 0; r < 4; ++r) pr[fm][r] = 0.f;
  }
#pragma unroll
  for (int fm = 0; fm < 4; ++fm) {
    const int m0 = bm + wm * 64 + fm * 16 + ((lane >> 4) << 2);
#pragma unroll
    for (int fn = 0; fn < 4; ++fn) {
      const int n0 = bn + wn * 64 + fn * 16 + (lane & 15);
#pragma unroll
      for (int r = 0; r < 4; ++r) {
        float v = acc[fm][fn][r];
        if (BIAS == 2) v += bias[m0 + r];
        if constexpr (sizeof(OT) == 2) Cb[(long)(m0 + r) * ldc + n0] = (OT)f2b(v);
        else Cb[(long)(m0 + r) * ldc + n0] = v;
        if (POOL) pr[fm][r] += v;
      }
    }
  }
  if (POOL) {
#pragma unroll
    for (int fm = 0; fm < 4; ++fm)
#pragma unroll
      for (int r = 0; r < 4; ++r) {
        float s = pr[fm][r];
        s += __shfl_xor(s, 1); s += __shfl_xor(s, 2);
        s += __shfl_xor(s, 4); s += __shfl_xor(s, 8);
        if ((lane & 15) == 0) {
          const int o = bm + wm * 64 + fm * 16 + ((lane >> 4) << 2) + r;
          poolpart[(long)(blockIdx.y * 2 + wn) * 2048 + bb * 256 + o] = s;
        }
      }
  }
}

// ---- depthwise 3x3 SAME; block = one image row (64 n) x 256 c.
// Writes xt [B,N,C] AND xtT [B,C,N] (LDS-staged, full-line stores). ----
__global__ __launch_bounds__(256) void dwconv2(const u16* __restrict__ x,
                                               const float* __restrict__ wdw,
                                               u16* __restrict__ y,
                                               u16* __restrict__ yT) {
  __shared__ float wsm[9][256];
  __shared__ u16 tb[256][72];
  const int t = threadIdx.x;
  for (int i = t; i < 2304; i += 256) wsm[i % 9][i / 9] = wdw[i];
  const int b = blockIdx.x >> 6, h = blockIdx.x & 63;
  const int c8 = (t & 31) * 8, wsub = t >> 5;
  const u16* base = x + ((long)b << 20);
  __syncthreads();
#pragma unroll
  for (int i = 0; i < 8; ++i) {
    const int w = wsub + 8 * i;
    float acc[8] = {0.f, 0.f, 0.f, 0.f, 0.f, 0.f, 0.f, 0.f};
#pragma unroll
    for (int ky = 0; ky < 3; ++ky) {
      const int hy = h + ky - 1;
      if ((unsigned)hy >= 64u) continue;
#pragma unroll
      for (int kx = 0; kx < 3; ++kx) {
        const int wx = w + kx - 1;
        if ((unsigned)wx >= 64u) continue;
        const s8v v = *(const s8v*)&base[(((hy << 6) + wx) << 8) + c8];
        const int kk = ky * 3 + kx;
        const fx4 wa = *(const fx4*)&wsm[kk][c8];
        const fx4 wb = *(const fx4*)&wsm[kk][c8 + 4];
#pragma unroll
        for (int j = 0; j < 4; ++j) {
          acc[j] += wa[j] * b2f((u16)v[j]);
          acc[4 + j] += wb[j] * b2f((u16)v[4 + j]);
        }
      }
    }
    s8v o;
#pragma unroll
    for (int j = 0; j < 8; ++j) o[j] = (short)f2b(acc[j]);
    *(s8v*)&y[((long)b << 20) + (long)(((h << 6) + w) << 8) + c8] = o;
#pragma unroll
    for (int j = 0; j < 8; ++j) tb[c8 + j][w] = (u16)o[j];
  }
  __syncthreads();
  u16* dst = yT + ((long)b << 20) + (long)t * 4096 + (h << 6);
#pragma unroll
  for (int j = 0; j < 8; ++j)
    *(s8v*)&dst[j * 8] = *(const s8v*)&tb[t][j * 8];
}

// ---- sum Gram split-K partials (4) -> hi/lo bf16 G2 [B,256,512] ----
__global__ __launch_bounds__(256) void gsplit(const float* __restrict__ part,
                                              u16* __restrict__ G2) {
  const int i4 = (blockIdx.x * 256 + threadIdx.x) * 4;    // over 524288
  fx4 s = {0.f, 0.f, 0.f, 0.f};
#pragma unroll
  for (int ss = 0; ss < 4; ++ss) s += *(const fx4*)(part + (long)ss * 524288 + i4);
  const int b = i4 >> 16, rem = i4 & 65535, e = rem >> 8, c0 = rem & 255;
  u16* d = G2 + (long)b * 131072 + (long)e * 512 + c0;
  s4v hi, lo;
#pragma unroll
  for (int j = 0; j < 4; ++j) {
    u16 h = f2b(s[j]);
    hi[j] = (short)h;
    lo[j] = (short)f2b(s[j] - b2f(h));
  }
  *(s4v*)d = hi;
  *(s4v*)(d + 256) = lo;
}

// ---- finalize rinv from diag partials + row softmax over d -> bf16 attn ----
__global__ __launch_bounds__(256) void softmax_g2(const float* __restrict__ araw,
                                                  const float* __restrict__ dpart,
                                                  u16* __restrict__ out) {
  const int wid = threadIdx.x >> 6, lane = threadIdx.x & 63;
  const int t = threadIdx.x;
  const int b = blockIdx.x >> 6;
  __shared__ float rq[256];
  float dq = dpart[b * 512 + t] + dpart[4096 + b * 512 + t] +
             dpart[8192 + b * 512 + t] + dpart[12288 + b * 512 + t];
  rq[t] = 1.f / fmaxf(sqrtf(fmaxf(dq, 0.f)), 1e-12f);
  __syncthreads();
  const long row = (long)blockIdx.x * 4 + wid;   // b*256 + c
  const int c = (int)(row & 255);
  const int ki = b * 512 + 256 + c;
  float dk = dpart[ki] + dpart[4096 + ki] + dpart[8192 + ki] + dpart[12288 + ki];
  const float rk = 1.f / fmaxf(sqrtf(fmaxf(dk, 0.f)), 1e-12f);
  fx4 v = ((const fx4*)(araw + row * 256))[lane];
  v[0] *= rk * rq[lane * 4];     v[1] *= rk * rq[lane * 4 + 1];
  v[2] *= rk * rq[lane * 4 + 2]; v[3] *= rk * rq[lane * 4 + 3];
  float m = fmaxf(fmaxf(v[0], v[1]), fmaxf(v[2], v[3]));
#pragma unroll
  for (int o = 32; o > 0; o >>= 1) m = fmaxf(m, __shfl_xor(m, o));
  float e0 = __expf(v[0] - m), e1 = __expf(v[1] - m);
  float e2 = __expf(v[2] - m), e3 = __expf(v[3] - m);
  float s4 = e0 + e1 + e2 + e3;
#pragma unroll
  for (int o = 32; o > 0; o >>= 1) s4 += __shfl_xor(s4, o);
  const float inv = 1.f / s4;
  u16* op = out + row * 256 + lane * 4;
  op[0] = f2b(e0 * inv); op[1] = f2b(e1 * inv);
  op[2] = f2b(e2 * inv); op[3] = f2b(e3 * inv);
}

// ---- SE gates: sum pooled partials + 2-layer MLP ----
__global__ __launch_bounds__(256) void se_gates(const float* __restrict__ poolpart,
                                                const float* __restrict__ w1d, const float* __restrict__ w2d,
                                                const float* __restrict__ w1s, const float* __restrict__ w2s,
                                                float* __restrict__ gd, float* __restrict__ gs) {
  const int b = blockIdx.x;
  const int t = threadIdx.x;
  __shared__ float p[256], hd[16], hs[16];
  float s = 0.f;
#pragma unroll 8
  for (int sl = 0; sl < 64; ++sl) s += poolpart[(long)sl * 2048 + b * 256 + t];
  p[t] = s * (1.f / 4096.f);
  __syncthreads();
  if (t < 16) {
    float ad = 0.f, as2 = 0.f;
    for (int j = 0; j < 256; ++j) {
      ad += w1d[t * 256 + j] * p[j];
      as2 += w1s[t * 256 + j] * p[j];
    }
    hd[t] = fmaxf(ad, 0.f);
    hs[t] = fmaxf(as2, 0.f);
  }
  __syncthreads();
  float ad = 0.f, as2 = 0.f;
#pragma unroll
  for (int r = 0; r < 16; ++r) {
    ad += w2d[t * 16 + r] * hd[r];
    as2 += w2s[t * 16 + r] * hs[r];
  }
  gd[b * 256 + t] = 1.f / (1.f + __expf(-ad));
  gs[b * 256 + t] = 1.f / (1.f + __expf(-as2));
}

// ---- final: out = outc(bf16)*gate + bf16 residual from catb (LDS transpose) ----
__global__ __launch_bounds__(256) void fuse_out2(const u16* __restrict__ oc,
                                                 const u16* __restrict__ cat,
                                                 const float* __restrict__ gd,
                                                 const float* __restrict__ gs,
                                                 float* __restrict__ od,
                                                 float* __restrict__ os) {
  __shared__ u16 td[32][68];
  __shared__ u16 ts2[32][68];
  const int b = blockIdx.z;
  const int c0 = blockIdx.y * 32;
  const int n0 = blockIdx.x * 64;
  const int t = threadIdx.x;
  {
    const int n = t >> 2, cj = (t & 3) * 8;
    const u16* cb = cat + ((long)b * 4096 + n0 + n) * 512 + c0 + cj;
    const s8v vd = *(const s8v*)cb;
    const s8v vs = *(const s8v*)(cb + 256);
#pragma unroll
    for (int j = 0; j < 8; ++j) {
      td[cj + j][n] = (u16)vd[j];
      ts2[cj + j][n] = (u16)vs[j];
    }
  }
  __syncthreads();
  const int c = t >> 3, no = (t & 7) * 8;
  const long obase = ((long)b * 256 + c0 + c) * 4096 + n0 + no;
  const float gdv = gd[b * 256 + c0 + c];
  const float gsv = gs[b * 256 + c0 + c];
  const s8v o8 = *(const s8v*)&oc[obase];
  fx4 r0, r1, q0, q1;
#pragma unroll
  for (int j = 0; j < 4; ++j) {
    const float vl = b2f((u16)o8[j]);
    const float vh = b2f((u16)o8[4 + j]);
    r0[j] = vl * gdv + b2f(td[c][no + j]);
    r1[j] = vh * gdv + b2f(td[c][no + 4 + j]);
    q0[j] = vl * gsv + b2f(ts2[c][no + j]);
    q1[j] = vh * gsv + b2f(ts2[c][no + 4 + j]);
  }
  *(fx4*)(od + obase) = r0; *(fx4*)(od + obase + 4) = r1;
  *(fx4*)(os + obase) = q0; *(fx4*)(os + obase + 4) = q1;
}

extern "C" void kernel_launch(void* const* d_in, const int* in_sizes, int n_in,
                              void* d_out, int out_size, void* d_ws, size_t ws_size,
                              hipStream_t stream) {
  const float* fd  = (const float*)d_in[0];
  const float* fs  = (const float*)d_in[1];
  const float* W0  = (const float*)d_in[2];
  const float* Wdw = (const float*)d_in[3];
  const float* Wq  = (const float*)d_in[4];
  const float* Wk  = (const float*)d_in[5];
  const float* Wv  = (const float*)d_in[6];
  const float* Wp  = (const float*)d_in[7];
  const float* bp  = (const float*)d_in[8];
  const float* Wsp = (const float*)d_in[9];
  const float* w1d = (const float*)d_in[10];
  const float* w2d = (const float*)d_in[11];
  const float* w1s = (const float*)d_in[12];
  const float* w2s = (const float*)d_in[13];

  char* ws = (char*)d_ws;
  u16* catb   = (u16*)(ws + 0);            // [B,N,512] bf16 33.5MB — LIVE until fuse_out2
  u16* x0b    = (u16*)(ws + 33554432);     // [B,N,256] 16.7MB; dead after dwconv2
  u16* outcb  = x0b;                       // [B,256,N] bf16 (reuse)
  u16* xtb    = (u16*)(ws + 50331648);     // [B,N,256] 16.7MB; live to outc gemm
  u16* xtT    = (u16*)(ws + 67108864);     // [B,256,N] 16.7MB; dead after gram
  float* part = (float*)(ws + 83886080);   // [4][B,256,256] fp32 8.4MB
  u16* G2     = (u16*)(ws + 92274688);     // [B,256,512] hi|lo 2.1MB
  u16* S2     = (u16*)(ws + 94371840);     // [B,256,512] hi|lo 2.1MB
  float* araw = (float*)(ws + 96468992);   // [B,256,256] fp32 2.1MB
  u16* attnb  = (u16*)(ws + 98566144);     // [B,256,256] 1MB
  u16* m1t    = (u16*)(ws + 99614720);     // [B,256,256] 1MB
  u16* wfin   = (u16*)(ws + 100663296);    // [B,256,256] 1MB
  u16* w0b    = (u16*)(ws + 101711872);    // 131072 el
  u16* wqk2   = (u16*)(ws + 101974016);    // [512,512]
  u16* wvtb   = (u16*)(ws + 102498304);    // [256,256]
  u16* wcb    = (u16*)(ws + 102629376);    // [256,256]
  float* bcb  = (float*)(ws + 102760448);  // 256
  float* dpart = (float*)(ws + 102761472); // [4][B*512] fp32 64KB
  float* poolpart = (float*)(ws + 102827008); // [64][B,256] fp32 512KB
  float* gdp  = (float*)(ws + 103351296);
  float* gsp  = (float*)(ws + 103359488);
  float* od  = (float*)d_out;
  float* osg = od + 8388608;

  prep<<<dim3(2048, 3), 256, 0, stream>>>(W0, Wq, Wk, Wv, w0b, wqk2, wvtb);
  wcmul<<<256, 256, 0, stream>>>(Wsp, Wp, bp, wcb, bcb);
  pack_cat<<<dim3(128, 16, 8), dim3(32, 8), 0, stream>>>(fd, fs, catb);
  // conv0: x0[b,n,o] = sum_c cat[b,n,c] W0[o,c]   M=4096 N=256 K=512
  gemm_nt<u16, 0, false, 0><<<dim3(32, 2, 8), 256, 0, stream>>>(
      catb, 2097152, 512, w0b, 0, 512, x0b, 1048576, 0, 256, nullptr, 512, 1,
      nullptr, nullptr, nullptr, nullptr);
  dwconv2<<<512, 256, 0, stream>>>(x0b, Wdw, xtb, xtT);
  // Gram: G[b,c,e] = sum_n xtT[b,c,n] xtT[b,e,n]   M=N=256 K=4096, split-K x4
  gemm_nt<float, 0, false, 0><<<dim3(2, 2, 32), 256, 0, stream>>>(
      xtT, 1048576, 4096, xtT, 1048576, 4096,
      part, 65536, 524288, 256, nullptr, 1024, 4, nullptr, nullptr, nullptr, nullptr);
  gsplit<<<512, 256, 0, stream>>>(part, G2);
  // SS = Wqk @ G  (M=512 N=256 K=512 hi|lo) with fused S2-split + diag partials
  gemm_nt<u16, 0, false, 1><<<dim3(4, 2, 8), 256, 0, stream>>>(
      wqk2, 0, 512, G2, 131072, 512, S2, 131072, 0, 512, nullptr, 512, 1,
      nullptr, Wq, Wk, dpart);
  // araw[b,c,d] = (Wk G Wq^T)[c,d]: A=[Wk|Wk], B=S2 hi|lo   M=N=256 K=512
  gemm_nt<float, 0, false, 0><<<dim3(2, 2, 8), 256, 0, stream>>>(
      wqk2 + 131072, 0, 512, S2, 131072, 512, araw, 65536, 0, 256, nullptr, 512, 1,
      nullptr, nullptr, nullptr, nullptr);
  softmax_g2<<<512, 256, 0, stream>>>(araw, dpart, attnb);
  // m1t[b,e,c] = sum_d WvT[e,d] attn[b,c,d]   M=N=256 K=256
  gemm_nt<u16, 0, false, 0><<<dim3(2, 2, 8), 256, 0, stream>>>(
      wvtb, 0, 256, attnb, 65536, 256, m1t, 65536, 0, 256, nullptr, 256, 1,
      nullptr, nullptr, nullptr, nullptr);
  // wfin[b,o,e] = sum_c Wc[o,c] m1t[b,e,c]   M=N=256 K=256
  gemm_nt<u16, 0, false, 0><<<dim3(2, 2, 8), 256, 0, stream>>>(
      wcb, 0, 256, m1t, 65536, 256, wfin, 65536, 0, 256, nullptr, 256, 1,
      nullptr, nullptr, nullptr, nullptr);
  // outc[b,o,n] = sum_e wfin[b,o,e] xt[b,n,e] + bc[o]   M=256 N=4096 K=256, +pool
  gemm_nt<u16, 2, true, 0><<<dim3(2, 32, 8), 256, 0, stream>>>(
      wfin, 65536, 256, xtb, 1048576, 256, outcb, 1048576, 0, 4096, bcb, 256, 1,
      poolpart, nullptr, nullptr, nullptr);
  se_gates<<<8, 256, 0, stream>>>(poolpart, w1d, w2d, w1s, w2s, gdp, gsp);
  fuse_out2<<<dim3(64, 8, 8), 256, 0, stream>>>(outcb, catb, gdp, gsp, od, osg);
}

// Round 5
// 182.813 us; speedup vs baseline: 1.0853x; 1.0853x over previous
//
#include <hip/hip_runtime.h>
#include <cstdint>

#define DEVI __device__ __forceinline__

using fx4 = __attribute__((ext_vector_type(4))) float;
using bf8 = __attribute__((ext_vector_type(8))) __bf16;
using s8v = __attribute__((ext_vector_type(8))) short;
using s4v = __attribute__((ext_vector_type(4))) short;
typedef unsigned short u16;
typedef unsigned int u32;

DEVI float b2f(u16 u) { return __builtin_bit_cast(float, (u32)u << 16); }
DEVI u16 f2b(float f) {
  u32 u = __builtin_bit_cast(u32, f);
  return (u16)((u + 0x7fffu + ((u >> 16) & 1u)) >> 16);
}

// async global->LDS, 16B per lane, dest = wave-uniform base + lane*16
#define GLOAD(g, l)                                                          \
  __builtin_amdgcn_global_load_lds(                                          \
      (const __attribute__((address_space(1))) unsigned int*)(g),            \
      (__attribute__((address_space(3))) unsigned int*)(l), 16, 0, 0)

// ---- weight prep: W0->bf16, Wqk2=[Wq|Wq ; Wk|Wk] bf16, WvT bf16 ----
__global__ __launch_bounds__(256) void prep(const float* __restrict__ W0,
                                            const float* __restrict__ Wq,
                                            const float* __restrict__ Wk,
                                            const float* __restrict__ Wv,
                                            u16* __restrict__ w0b,
                                            u16* __restrict__ wqk2,
                                            u16* __restrict__ wvtb) {
  const int i = blockIdx.x * 256 + threadIdx.x;
  if (blockIdx.y == 0) {
    if (i < 131072) w0b[i] = f2b(W0[i]);
  } else if (blockIdx.y == 1) {
    if (i < 524288) {
      const int row = i >> 9, c = i & 511;
      const float* src = (row < 256) ? Wq : Wk;
      wqk2[i] = f2b(src[((row & 255) << 8) + (c & 255)]);
    }
  } else {
    if (i < 65536) {
      const int e = i >> 8, d = i & 255;
      wvtb[i] = f2b(Wv[d * 256 + e]);   // WvT[e,d] = Wv[d,e]
    }
  }
}

// ---- Wc = Wsp @ Wp (bf16), bc = Wsp @ bp (fp32) ----
__global__ __launch_bounds__(256) void wcmul(const float* __restrict__ Wsp,
                                             const float* __restrict__ Wp,
                                             const float* __restrict__ bp,
                                             u16* __restrict__ wcb, float* __restrict__ bc) {
  const int o = blockIdx.x, t = threadIdx.x;
  __shared__ float row[256];
  __shared__ float red[4];
  row[t] = Wsp[o * 256 + t];
  __syncthreads();
  float acc = 0.f;
  for (int c = 0; c < 256; ++c) acc += row[c] * Wp[c * 256 + t];
  wcb[o * 256 + t] = f2b(acc);
  float pb = row[t] * bp[t];
#pragma unroll
  for (int m = 32; m > 0; m >>= 1) pb += __shfl_xor(pb, m);
  if ((t & 63) == 0) red[t >> 6] = pb;
  __syncthreads();
  if (t == 0) bc[o] = red[0] + red[1] + red[2] + red[3];
}

// ---- concat + transpose: fd,fs [B,C,N] fp32 -> cat_t [B,N,2C] bf16 ----
__global__ void pack_cat(const float* __restrict__ fd, const float* __restrict__ fs,
                         u16* __restrict__ out) {
  __shared__ float t[32][33];
  const int b = blockIdx.z;
  const int n0 = blockIdx.x * 32;
  const int g = blockIdx.y;
  const float* src = (g < 8) ? fd : fs;
  const int c0 = (g & 7) * 32;
  const int ccol0 = g * 32;
  const int tx = threadIdx.x;
  const int ty = threadIdx.y;
  const float* sp = src + ((long)b * 256 + c0) * 4096 + n0;
#pragma unroll
  for (int i = 0; i < 4; ++i) {
    int c = ty + i * 8;
    t[c][tx] = sp[(long)c * 4096 + tx];
  }
  __syncthreads();
  u16* op = out + ((long)b * 4096 + n0) * 512 + ccol0;
#pragma unroll
  for (int i = 0; i < 4; ++i) {
    int r = ty + i * 8;
    op[(long)r * 512 + tx] = f2b(t[tx][r]);
  }
}

// ---- bf16 NT GEMM: C[m,n] = sum_k A[m,k]*B[n,k] ----
// 128x128 tile, BK=64, 4 waves; global_load_lds(16B) staging with
// pre-swizzled SOURCE address (LDS dest linear, XOR-swizzled read).
// BIAS: 0 none, 2 bias[m]. POOL: per-tile row sums.
// EPI: 0 normal C write; 1 = S2 hi/lo write (rows<256) + diag partials.
template <typename OT, int BIAS, bool POOL, int EPI>
__global__ __launch_bounds__(256) void gemm_nt(
    const u16* __restrict__ A, long sA, int lda,
    const u16* __restrict__ B, long sB, int ldb,
    OT* __restrict__ C, long sC, long sCs, int ldc,
    const float* __restrict__ bias, int Keff, int ksplit,
    float* __restrict__ poolpart,
    const float* __restrict__ wqf, const float* __restrict__ wkf,
    float* __restrict__ dpart) {
  __shared__ u16 ldsA[128 * 64];
  __shared__ u16 ldsB[128 * 64];
  const int z = blockIdx.z;
  const int bb = z / ksplit;
  const int ss = z - bb * ksplit;
  const int bm = blockIdx.x * 128;
  const int bn = blockIdx.y * 128;
  const u16* Ab = A + bb * sA + (long)ss * Keff + (long)bm * lda;
  const u16* Bb = B + bb * sB + (long)ss * Keff + (long)bn * ldb;
  const int tid = threadIdx.x;
  const int wid = tid >> 6;
  const int lane = tid & 63;
  const int wm = wid >> 1, wn = wid & 1;
  const int srow = tid >> 3;
  const int slot = tid & 7;

  fx4 acc[4][4] = {};
  for (int kt = 0; kt < Keff; kt += 64) {
#pragma unroll
    for (int i = 0; i < 4; ++i) {
      const int row = i * 32 + srow;
      const int kq = slot ^ (row & 7);
      GLOAD(Ab + (long)row * lda + kt + kq * 8, &ldsA[i * 2048 + wid * 512]);
      GLOAD(Bb + (long)row * ldb + kt + kq * 8, &ldsB[i * 2048 + wid * 512]);
    }
    __syncthreads();
#pragma unroll
    for (int ko = 0; ko < 2; ++ko) {
      bf8 af[4], bfr[4];
      const int kq = ko * 4 + (lane >> 4);
#pragma unroll
      for (int f = 0; f < 4; ++f) {
        const int ar = wm * 64 + f * 16 + (lane & 15);
        af[f] = *(const bf8*)&ldsA[ar * 64 + ((kq ^ (ar & 7)) * 8)];
        const int br = wn * 64 + f * 16 + (lane & 15);
        bfr[f] = *(const bf8*)&ldsB[br * 64 + ((kq ^ (br & 7)) * 8)];
      }
#pragma unroll
      for (int fm = 0; fm < 4; ++fm)
#pragma unroll
        for (int fn = 0; fn < 4; ++fn)
          acc[fm][fn] = __builtin_amdgcn_mfma_f32_16x16x32_bf16(af[fm], bfr[fn], acc[fm][fn], 0, 0, 0);
    }
    __syncthreads();
  }
  if constexpr (EPI == 1) {
    // S2 hi/lo write for rows<256 + diag partials for all rows
    u16* S2b = (u16*)C + bb * sC;
    float dp[4][4];
#pragma unroll
    for (int fm = 0; fm < 4; ++fm)
#pragma unroll
      for (int r = 0; r < 4; ++r) dp[fm][r] = 0.f;
#pragma unroll
    for (int fm = 0; fm < 4; ++fm) {
      const int m0 = bm + wm * 64 + fm * 16 + ((lane >> 4) << 2);
#pragma unroll
      for (int fn = 0; fn < 4; ++fn) {
        const int n0 = bn + wn * 64 + fn * 16 + (lane & 15);
#pragma unroll
        for (int r = 0; r < 4; ++r) {
          const float v = acc[fm][fn][r];
          const int m = m0 + r;
          if (m < 256) {
            const u16 hi = f2b(v);
            S2b[(long)m * 512 + n0] = hi;
            S2b[(long)m * 512 + 256 + n0] = f2b(v - b2f(hi));
          }
          const float* wr = (m < 256) ? (wqf + (long)m * 256) : (wkf + (long)(m - 256) * 256);
          dp[fm][r] += v * wr[n0];
        }
      }
    }
#pragma unroll
    for (int fm = 0; fm < 4; ++fm)
#pragma unroll
      for (int r = 0; r < 4; ++r) {
        float s = dp[fm][r];
        s += __shfl_xor(s, 1); s += __shfl_xor(s, 2);
        s += __shfl_xor(s, 4); s += __shfl_xor(s, 8);
        if ((lane & 15) == 0) {
          const int m = bm + wm * 64 + fm * 16 + ((lane >> 4) << 2) + r;
          dpart[(long)(blockIdx.y * 2 + wn) * 4096 + bb * 512 + m] = s;
        }
      }
    return;
  }
  OT* Cb = C + bb * sC + ss * sCs;
  float pr[4][4];
  if (POOL) {
#pragma unroll
    for (int fm = 0; fm < 4; ++fm)
#pragma unroll
      for (int r = 0; r < 4; ++r) pr[fm][r] = 0.f;
  }
#pragma unroll
  for (int fm = 0; fm < 4; ++fm) {
    const int m0 = bm + wm * 64 + fm * 16 + ((lane >> 4) << 2);
#pragma unroll
    for (int fn = 0; fn < 4; ++fn) {
      const int n0 = bn + wn * 64 + fn * 16 + (lane & 15);
#pragma unroll
      for (int r = 0; r < 4; ++r) {
        float v = acc[fm][fn][r];
        if (BIAS == 2) v += bias[m0 + r];
        if constexpr (sizeof(OT) == 2) Cb[(long)(m0 + r) * ldc + n0] = (OT)f2b(v);
        else Cb[(long)(m0 + r) * ldc + n0] = v;
        if (POOL) pr[fm][r] += v;
      }
    }
  }
  if (POOL) {
#pragma unroll
    for (int fm = 0; fm < 4; ++fm)
#pragma unroll
      for (int r = 0; r < 4; ++r) {
        float s = pr[fm][r];
        s += __shfl_xor(s, 1); s += __shfl_xor(s, 2);
        s += __shfl_xor(s, 4); s += __shfl_xor(s, 8);
        if ((lane & 15) == 0) {
          const int o = bm + wm * 64 + fm * 16 + ((lane >> 4) << 2) + r;
          poolpart[(long)(blockIdx.y * 2 + wn) * 2048 + bb * 256 + o] = s;
        }
      }
  }
}

// ---- depthwise 3x3 SAME, [B,N,C] bf16 layout (high-occupancy version) ----
__global__ __launch_bounds__(256) void dwconv3x3(const u16* __restrict__ x,
                                                 const float* __restrict__ wdw,
                                                 u16* __restrict__ y) {
  __shared__ float w[9][256];
  const int t = threadIdx.x;
  for (int i = t; i < 2304; i += 256) w[i % 9][i / 9] = wdw[i];
  __syncthreads();
  const int nb = blockIdx.x;
  const int b = nb >> 9;
  const int n0 = (nb & 511) << 3;
  const int tn = t >> 5;
  const int tc = (t & 31) << 3;
  const int n = n0 + tn;
  const int hh = n >> 6, ww2 = n & 63;
  const u16* base = x + ((long)b << 20);
  float acc[8] = {0.f, 0.f, 0.f, 0.f, 0.f, 0.f, 0.f, 0.f};
#pragma unroll
  for (int ky = 0; ky < 3; ++ky) {
    const int hy = hh + ky - 1;
    if ((unsigned)hy >= 64u) continue;
#pragma unroll
    for (int kx = 0; kx < 3; ++kx) {
      const int wx = ww2 + kx - 1;
      if ((unsigned)wx >= 64u) continue;
      const s8v v = *(const s8v*)&base[(((hy << 6) + wx) << 8) + tc];
      const int kk = ky * 3 + kx;
      const fx4 wa = *(const fx4*)&w[kk][tc];
      const fx4 wb = *(const fx4*)&w[kk][tc + 4];
#pragma unroll
      for (int j = 0; j < 4; ++j) {
        acc[j] += wa[j] * b2f((u16)v[j]);
        acc[4 + j] += wb[j] * b2f((u16)v[4 + j]);
      }
    }
  }
  s8v o;
#pragma unroll
  for (int j = 0; j < 8; ++j) o[j] = (short)f2b(acc[j]);
  *(s8v*)&y[((long)b << 20) + ((long)n << 8) + tc] = o;
}

// ---- bf16 transpose: xt [B,4096,256] -> xtT [B,256,4096] ----
__global__ void btrans(const u16* __restrict__ x, u16* __restrict__ y) {
  __shared__ u16 t[32][34];
  const int b = blockIdx.z;
  const int n0 = blockIdx.x * 32;
  const int c0 = blockIdx.y * 32;
  const int tx = threadIdx.x, ty = threadIdx.y;
  const u16* sp = x + (long)b * 1048576 + (long)n0 * 256 + c0;
#pragma unroll
  for (int j = 0; j < 4; ++j) {
    int i = ty + j * 8;
    t[i][tx] = sp[(long)i * 256 + tx];
  }
  __syncthreads();
  u16* op = y + (long)b * 1048576 + (long)c0 * 4096 + n0;
#pragma unroll
  for (int j = 0; j < 4; ++j) {
    int r = ty + j * 8;
    op[(long)r * 4096 + tx] = t[tx][r];
  }
}

// ---- sum Gram split-K partials (8) -> hi/lo bf16 G2 [B,256,512] ----
__global__ __launch_bounds__(256) void gsplit(const float* __restrict__ part,
                                              u16* __restrict__ G2) {
  const int i4 = (blockIdx.x * 256 + threadIdx.x) * 4;    // over 524288
  fx4 s = {0.f, 0.f, 0.f, 0.f};
#pragma unroll
  for (int ss = 0; ss < 8; ++ss) s += *(const fx4*)(part + (long)ss * 524288 + i4);
  const int b = i4 >> 16, rem = i4 & 65535, e = rem >> 8, c0 = rem & 255;
  u16* d = G2 + (long)b * 131072 + (long)e * 512 + c0;
  s4v hi, lo;
#pragma unroll
  for (int j = 0; j < 4; ++j) {
    u16 h = f2b(s[j]);
    hi[j] = (short)h;
    lo[j] = (short)f2b(s[j] - b2f(h));
  }
  *(s4v*)d = hi;
  *(s4v*)(d + 256) = lo;
}

// ---- finalize rinv from diag partials + row softmax over d -> bf16 attn ----
__global__ __launch_bounds__(256) void softmax_g2(const float* __restrict__ araw,
                                                  const float* __restrict__ dpart,
                                                  u16* __restrict__ out) {
  const int wid = threadIdx.x >> 6, lane = threadIdx.x & 63;
  const int t = threadIdx.x;
  const int b = blockIdx.x >> 6;
  __shared__ float rq[256];
  float dq = dpart[b * 512 + t] + dpart[4096 + b * 512 + t] +
             dpart[8192 + b * 512 + t] + dpart[12288 + b * 512 + t];
  rq[t] = 1.f / fmaxf(sqrtf(fmaxf(dq, 0.f)), 1e-12f);
  __syncthreads();
  const long row = (long)blockIdx.x * 4 + wid;   // b*256 + c
  const int c = (int)(row & 255);
  const int ki = b * 512 + 256 + c;
  float dk = dpart[ki] + dpart[4096 + ki] + dpart[8192 + ki] + dpart[12288 + ki];
  const float rk = 1.f / fmaxf(sqrtf(fmaxf(dk, 0.f)), 1e-12f);
  fx4 v = ((const fx4*)(araw + row * 256))[lane];
  v[0] *= rk * rq[lane * 4];     v[1] *= rk * rq[lane * 4 + 1];
  v[2] *= rk * rq[lane * 4 + 2]; v[3] *= rk * rq[lane * 4 + 3];
  float m = fmaxf(fmaxf(v[0], v[1]), fmaxf(v[2], v[3]));
#pragma unroll
  for (int o = 32; o > 0; o >>= 1) m = fmaxf(m, __shfl_xor(m, o));
  float e0 = __expf(v[0] - m), e1 = __expf(v[1] - m);
  float e2 = __expf(v[2] - m), e3 = __expf(v[3] - m);
  float s4 = e0 + e1 + e2 + e3;
#pragma unroll
  for (int o = 32; o > 0; o >>= 1) s4 += __shfl_xor(s4, o);
  const float inv = 1.f / s4;
  u16* op = out + row * 256 + lane * 4;
  op[0] = f2b(e0 * inv); op[1] = f2b(e1 * inv);
  op[2] = f2b(e2 * inv); op[3] = f2b(e3 * inv);
}

// ---- SE gates: sum pooled partials + 2-layer MLP ----
__global__ __launch_bounds__(256) void se_gates(const float* __restrict__ poolpart,
                                                const float* __restrict__ w1d, const float* __restrict__ w2d,
                                                const float* __restrict__ w1s, const float* __restrict__ w2s,
                                                float* __restrict__ gd, float* __restrict__ gs) {
  const int b = blockIdx.x;
  const int t = threadIdx.x;
  __shared__ float p[256], hd[16], hs[16];
  float s = 0.f;
#pragma unroll 8
  for (int sl = 0; sl < 64; ++sl) s += poolpart[(long)sl * 2048 + b * 256 + t];
  p[t] = s * (1.f / 4096.f);
  __syncthreads();
  if (t < 16) {
    float ad = 0.f, as2 = 0.f;
    for (int j = 0; j < 256; ++j) {
      ad += w1d[t * 256 + j] * p[j];
      as2 += w1s[t * 256 + j] * p[j];
    }
    hd[t] = fmaxf(ad, 0.f);
    hs[t] = fmaxf(as2, 0.f);
  }
  __syncthreads();
  float ad = 0.f, as2 = 0.f;
#pragma unroll
  for (int r = 0; r < 16; ++r) {
    ad += w2d[t * 16 + r] * hd[r];
    as2 += w2s[t * 16 + r] * hs[r];
  }
  gd[b * 256 + t] = 1.f / (1.f + __expf(-ad));
  gs[b * 256 + t] = 1.f / (1.f + __expf(-as2));
}

// ---- final: out = outc(bf16)*gate + bf16 residual from catb (LDS transpose) ----
__global__ __launch_bounds__(256) void fuse_out2(const u16* __restrict__ oc,
                                                 const u16* __restrict__ cat,
                                                 const float* __restrict__ gd,
                                                 const float* __restrict__ gs,
                                                 float* __restrict__ od,
                                                 float* __restrict__ os) {
  __shared__ u16 td[32][68];
  __shared__ u16 ts2[32][68];
  const int b = blockIdx.z;
  const int c0 = blockIdx.y * 32;
  const int n0 = blockIdx.x * 64;
  const int t = threadIdx.x;
  {
    const int n = t >> 2, cj = (t & 3) * 8;
    const u16* cb = cat + ((long)b * 4096 + n0 + n) * 512 + c0 + cj;
    const s8v vd = *(const s8v*)cb;
    const s8v vs = *(const s8v*)(cb + 256);
#pragma unroll
    for (int j = 0; j < 8; ++j) {
      td[cj + j][n] = (u16)vd[j];
      ts2[cj + j][n] = (u16)vs[j];
    }
  }
  __syncthreads();
  const int c = t >> 3, no = (t & 7) * 8;
  const long obase = ((long)b * 256 + c0 + c) * 4096 + n0 + no;
  const float gdv = gd[b * 256 + c0 + c];
  const float gsv = gs[b * 256 + c0 + c];
  const s8v o8 = *(const s8v*)&oc[obase];
  fx4 r0, r1, q0, q1;
#pragma unroll
  for (int j = 0; j < 4; ++j) {
    const float vl = b2f((u16)o8[j]);
    const float vh = b2f((u16)o8[4 + j]);
    r0[j] = vl * gdv + b2f(td[c][no + j]);
    r1[j] = vh * gdv + b2f(td[c][no + 4 + j]);
    q0[j] = vl * gsv + b2f(ts2[c][no + j]);
    q1[j] = vh * gsv + b2f(ts2[c][no + 4 + j]);
  }
  *(fx4*)(od + obase) = r0; *(fx4*)(od + obase + 4) = r1;
  *(fx4*)(os + obase) = q0; *(fx4*)(os + obase + 4) = q1;
}

extern "C" void kernel_launch(void* const* d_in, const int* in_sizes, int n_in,
                              void* d_out, int out_size, void* d_ws, size_t ws_size,
                              hipStream_t stream) {
  const float* fd  = (const float*)d_in[0];
  const float* fs  = (const float*)d_in[1];
  const float* W0  = (const float*)d_in[2];
  const float* Wdw = (const float*)d_in[3];
  const float* Wq  = (const float*)d_in[4];
  const float* Wk  = (const float*)d_in[5];
  const float* Wv  = (const float*)d_in[6];
  const float* Wp  = (const float*)d_in[7];
  const float* bp  = (const float*)d_in[8];
  const float* Wsp = (const float*)d_in[9];
  const float* w1d = (const float*)d_in[10];
  const float* w2d = (const float*)d_in[11];
  const float* w1s = (const float*)d_in[12];
  const float* w2s = (const float*)d_in[13];

  char* ws = (char*)d_ws;
  u16* catb   = (u16*)(ws + 0);            // [B,N,512] bf16 33.5MB — LIVE until fuse_out2
  u16* x0b    = (u16*)(ws + 33554432);     // [B,N,256] 16.7MB; dead after dwconv
  u16* outcb  = x0b;                       // [B,256,N] bf16 (reuse)
  u16* xtb    = (u16*)(ws + 50331648);     // [B,N,256] 16.7MB; live to outc gemm
  u16* xtT    = (u16*)(ws + 67108864);     // [B,256,N] 16.7MB; dead after gram
  float* part = (float*)(ws + 83886080);   // [8][B,256,256] fp32 16.7MB
  u16* G2     = (u16*)(ws + 100663296);    // [B,256,512] hi|lo 2.1MB
  u16* S2     = (u16*)(ws + 102760448);    // [B,256,512] hi|lo 2.1MB
  float* araw = (float*)(ws + 104857600);  // [B,256,256] fp32 2.1MB
  u16* attnb  = (u16*)(ws + 106954752);    // [B,256,256] 1MB
  u16* m1t    = (u16*)(ws + 108003328);    // [B,256,256] 1MB
  u16* wfin   = (u16*)(ws + 109051904);    // [B,256,256] 1MB
  u16* w0b    = (u16*)(ws + 110100480);    // 131072 el
  u16* wqk2   = (u16*)(ws + 110362624);    // [512,512]
  u16* wvtb   = (u16*)(ws + 110886912);    // [256,256]
  u16* wcb    = (u16*)(ws + 111017984);    // [256,256]
  float* bcb  = (float*)(ws + 111149056);  // 256
  float* dpart = (float*)(ws + 111150080); // [4][B*512] fp32 64KB
  float* poolpart = (float*)(ws + 111215616); // [64][B,256] fp32 512KB
  float* gdp  = (float*)(ws + 111739904);
  float* gsp  = (float*)(ws + 111748096);
  float* od  = (float*)d_out;
  float* osg = od + 8388608;

  prep<<<dim3(2048, 3), 256, 0, stream>>>(W0, Wq, Wk, Wv, w0b, wqk2, wvtb);
  wcmul<<<256, 256, 0, stream>>>(Wsp, Wp, bp, wcb, bcb);
  pack_cat<<<dim3(128, 16, 8), dim3(32, 8), 0, stream>>>(fd, fs, catb);
  // conv0: x0[b,n,o] = sum_c cat[b,n,c] W0[o,c]   M=4096 N=256 K=512
  gemm_nt<u16, 0, false, 0><<<dim3(32, 2, 8), 256, 0, stream>>>(
      catb, 2097152, 512, w0b, 0, 512, x0b, 1048576, 0, 256, nullptr, 512, 1,
      nullptr, nullptr, nullptr, nullptr);
  dwconv3x3<<<4096, 256, 0, stream>>>(x0b, Wdw, xtb);
  btrans<<<dim3(128, 8, 8), dim3(32, 8), 0, stream>>>(xtb, xtT);
  // Gram: G[b,c,e] = sum_n xtT[b,c,n] xtT[b,e,n]   M=N=256 K=4096, split-K x8
  gemm_nt<float, 0, false, 0><<<dim3(2, 2, 64), 256, 0, stream>>>(
      xtT, 1048576, 4096, xtT, 1048576, 4096,
      part, 65536, 524288, 256, nullptr, 512, 8, nullptr, nullptr, nullptr, nullptr);
  gsplit<<<512, 256, 0, stream>>>(part, G2);
  // SS = Wqk @ G  (M=512 N=256 K=512 hi|lo) with fused S2-split + diag partials
  gemm_nt<u16, 0, false, 1><<<dim3(4, 2, 8), 256, 0, stream>>>(
      wqk2, 0, 512, G2, 131072, 512, S2, 131072, 0, 512, nullptr, 512, 1,
      nullptr, Wq, Wk, dpart);
  // araw[b,c,d] = (Wk G Wq^T)[c,d]: A=[Wk|Wk], B=S2 hi|lo   M=N=256 K=512
  gemm_nt<float, 0, false, 0><<<dim3(2, 2, 8), 256, 0, stream>>>(
      wqk2 + 131072, 0, 512, S2, 131072, 512, araw, 65536, 0, 256, nullptr, 512, 1,
      nullptr, nullptr, nullptr, nullptr);
  softmax_g2<<<512, 256, 0, stream>>>(araw, dpart, attnb);
  // m1t[b,e,c] = sum_d WvT[e,d] attn[b,c,d]   M=N=256 K=256
  gemm_nt<u16, 0, false, 0><<<dim3(2, 2, 8), 256, 0, stream>>>(
      wvtb, 0, 256, attnb, 65536, 256, m1t, 65536, 0, 256, nullptr, 256, 1,
      nullptr, nullptr, nullptr, nullptr);
  // wfin[b,o,e] = sum_c Wc[o,c] m1t[b,e,c]   M=N=256 K=256
  gemm_nt<u16, 0, false, 0><<<dim3(2, 2, 8), 256, 0, stream>>>(
      wcb, 0, 256, m1t, 65536, 256, wfin, 65536, 0, 256, nullptr, 256, 1,
      nullptr, nullptr, nullptr, nullptr);
  // outc[b,o,n] = sum_e wfin[b,o,e] xt[b,n,e] + bc[o]   M=256 N=4096 K=256, +pool
  gemm_nt<u16, 2, true, 0><<<dim3(2, 32, 8), 256, 0, stream>>>(
      wfin, 65536, 256, xtb, 1048576, 256, outcb, 1048576, 0, 4096, bcb, 256, 1,
      poolpart, nullptr, nullptr, nullptr);
  se_gates<<<8, 256, 0, stream>>>(poolpart, w1d, w2d, w1s, w2s, gdp, gsp);
  fuse_out2<<<dim3(64, 8, 8), 256, 0, stream>>>(outcb, catb, gdp, gsp, od, osg);
}